// Round 1
// baseline (169.348 us; speedup 1.0000x reference)
//
#include <hip/hip_runtime.h>

typedef unsigned short u16;
typedef unsigned int   u32;

typedef __attribute__((ext_vector_type(4))) float  f32x4;
typedef __attribute__((ext_vector_type(8))) __bf16 bf16x8;

#define B_  2
#define L_  2048
#define H_  16

// ---------- bf16 helpers ----------
__device__ static inline u16 f2bf(float f) {
  u32 u = __builtin_bit_cast(u32, f);
  u32 r = u + 0x7fffu + ((u >> 16) & 1u);
  return (u16)(r >> 16);
}
__device__ static inline u32 pack2(float a, float b) {   // RTNE pair pack
  return (u32)f2bf(a) | ((u32)f2bf(b) << 16);
}
// one-instruction truncating pair pack: dst = {hi16(b), hi16(a)} via v_perm_b32
__device__ static inline u32 pack2t(float a, float b) {
  return __builtin_amdgcn_perm(__builtin_bit_cast(u32, b),
                               __builtin_bit_cast(u32, a), 0x07060302u);
}

// async global->LDS, 16B/lane. LDS dest = wave-uniform base + lane*16.
__device__ static inline void gload_lds16(const u16* g, u16* lds) {
  __builtin_amdgcn_global_load_lds((__attribute__((address_space(1))) void*)(g),
                                   (__attribute__((address_space(3))) void*)(lds),
                                   16, 0, 0);
}

// ---------------------------------------------------------------------------
// fused fp32 -> bf16 pack for x, Wqkv, Wo (RTNE — GEMM inputs keep accuracy).
// NEW: the softmax 1/sqrt(dk)=0.125 scale is folded into the W_q rows
// (rows < 1024 of W_qkv). Power-of-two => bf16 mantissas identical, so the
// attention P values are bit-identical while saving 16 v_mul per phase.
// ---------------------------------------------------------------------------
__global__ __launch_bounds__(256) void cvt3_kernel(
    const float4* __restrict__ a, uint2* __restrict__ ao, int na,
    const float4* __restrict__ b, uint2* __restrict__ bo, int nb,
    const float4* __restrict__ c, uint2* __restrict__ co, int nc)
{
  const int step = gridDim.x * 256;
  constexpr int nq = 1024 * 1024 / 4;          // float4 count of the W_q rows
  for (int i = blockIdx.x * 256 + threadIdx.x; i < na; i += step) {
    float4 f = a[i];
    ao[i] = make_uint2(pack2(f.x, f.y), pack2(f.z, f.w));
  }
  for (int i = blockIdx.x * 256 + threadIdx.x; i < nb; i += step) {
    float4 f = b[i];
    const float s = (i < nq) ? 0.125f : 1.0f;
    bo[i] = make_uint2(pack2(f.x * s, f.y * s), pack2(f.z * s, f.w * s));
  }
  for (int i = blockIdx.x * 256 + threadIdx.x; i < nc; i += step) {
    float4 f = c[i];
    co[i] = make_uint2(pack2(f.x, f.y), pack2(f.z, f.w));
  }
}

// ---------------------------------------------------------------------------
// GEMM: C[M,N] = A[M,K] @ Bt[N,K]^T, bf16 in, fp32 MFMA accumulate.
// m97 structure + source-permuted XOR chunk swizzle (R6). Unchanged this round.
// ---------------------------------------------------------------------------
template <bool OUT_F32, int NT, bool DBUF>
__global__ __launch_bounds__(256) void gemm_bt_kernel(
    const u16* __restrict__ A, const u16* __restrict__ Bt, void* __restrict__ Cv,
    const int K, const int N)
{
  constexpr int NB = DBUF ? 2 : 1;
  constexpr int JT = NT / 32;                    // j-tiles per wave
  __shared__ __attribute__((aligned(16))) u16 Al[NB][128 * 64];
  __shared__ __attribute__((aligned(16))) u16 Bl[NB][NT * 64];

  const int tid  = threadIdx.x;
  const int w    = tid >> 6;
  const int lane = tid & 63;
  const int m0 = blockIdx.y * 128;
  const int n0 = blockIdx.x * NT;
  const int mo = (w >> 1) * 64;
  const int no = (w & 1) * (NT / 2);

  const int sr8  = lane >> 3;                    // staging row-in-group
  const int scol = (((lane & 7) ^ ((lane >> 3) & 7)) * 8);   // swizzled source chunk

  const f32x4 zero = {0.f, 0.f, 0.f, 0.f};
  f32x4 acc[4][JT];
  #pragma unroll
  for (int i = 0; i < 4; ++i)
    #pragma unroll
    for (int j = 0; j < JT; ++j) acc[i][j] = zero;

  const int frow = lane & 15;
  const int fg   = lane >> 4;

  auto stage = [&](int buf, int k0) {
    #pragma unroll
    for (int inst = 0; inst < 4; ++inst) {
      const int r = w * 32 + inst * 8 + sr8;
      gload_lds16(A + (size_t)(m0 + r) * K + k0 + scol, &Al[buf][(w * 32 + inst * 8) * 64]);
    }
    #pragma unroll
    for (int inst = 0; inst < NT / 32; ++inst) {
      const int r = w * (NT / 4) + inst * 8 + sr8;
      gload_lds16(Bt + (size_t)(n0 + r) * K + k0 + scol, &Bl[buf][(w * (NT / 4) + inst * 8) * 64]);
    }
  };

  if (DBUF) stage(0, 0);

  int cur = 0;
  for (int k0 = 0; k0 < K; k0 += 64) {
    __syncthreads();
    if (DBUF) {
      if (k0 + 64 < K) stage(cur ^ 1, k0 + 64);
    } else {
      stage(0, k0);
      __syncthreads();
    }
    #pragma unroll
    for (int ks = 0; ks < 2; ++ks) {
      const int fco = ((ks * 4 + fg) ^ (frow & 7)) * 8;      // swizzled read chunk
      bf16x8 af[4], bfr[JT];
      #pragma unroll
      for (int i = 0; i < 4; ++i)
        af[i] = *(const bf16x8*)&Al[cur][(mo + i * 16 + frow) * 64 + fco];
      #pragma unroll
      for (int j = 0; j < JT; ++j)
        bfr[j] = *(const bf16x8*)&Bl[cur][(no + j * 16 + frow) * 64 + fco];
      #pragma unroll
      for (int i = 0; i < 4; ++i)
        #pragma unroll
        for (int j = 0; j < JT; ++j)
          acc[i][j] = __builtin_amdgcn_mfma_f32_16x16x32_bf16(af[i], bfr[j], acc[i][j], 0, 0, 0);
    }
    if (DBUF) cur ^= 1;
  }

  const int crow0 = m0 + mo + (lane >> 4) * 4;
  const int ccol0 = n0 + no + (lane & 15);
  #pragma unroll
  for (int i = 0; i < 4; ++i)
    #pragma unroll
    for (int j = 0; j < JT; ++j)
      #pragma unroll
      for (int r = 0; r < 4; ++r) {
        const size_t idx = (size_t)(crow0 + i * 16 + r) * N + (ccol0 + j * 16);
        if (OUT_F32) ((float*)Cv)[idx] = acc[i][j][r];
        else         ((u16*)Cv)[idx]   = f2bf(acc[i][j][r]);
      }
}

// ---------------------------------------------------------------------------
// MFMA causal flash attention — R10: occupancy restructure.
// 256 threads (4 waves), one q-tile per block, grid 32 bh x 32 qt = 1024 blocks.
// LDS 40960 B  =>  4 blocks/CU co-resident (4 x 40960 = 163840 = full LDS),
// 16 waves/CU, 4-wave barriers, 4 independent blocks to hide phase latency.
// Split-K combine removed. Static qt remap balances causal work so each
// CU-stride-256 group of blocks sums to 66 tiles: {a, 31-a, 8+a, 23-a}.
// Softmax scale pre-folded into W_q (bit-identical P). T5 setprio on MFMA.
// Transposed orientation, swizzled LDS layouts, dbuf prefetch kept from R9.
// ---------------------------------------------------------------------------
__global__ __launch_bounds__(256) void attn_mfma_kernel(const u16* __restrict__ qkv,
                                                        u16* __restrict__ y)
{
  __shared__ __attribute__((aligned(16))) unsigned char smem[40960];

  const int tid  = threadIdx.x;
  const int w    = tid >> 6;                   // wave 0..3
  const int lane = tid & 63;
  const int fr   = lane & 15;
  const int fg   = lane >> 4;
  const int bh   = blockIdx.x;                 // bh on x => XCD affinity
  const int bb   = bh >> 4;
  const int hh   = bh & 15;
  const size_t rb = (size_t)bb * L_;

  // load-balance remap: blocks at id, id+256, id+512, id+768 (same CU under
  // round-robin dispatch) get qt = {a, 31-a, 8+a, 23-a} -> 66 tiles total.
  const int a  = blockIdx.y & 7;
  const int cc = blockIdx.y >> 3;
  const int qt = (cc == 0) ? a : (cc == 1) ? (31 - a) : (cc == 2) ? (8 + a) : (23 - a);

  u16* Kt  = (u16*)(smem);                     // [buf*4096 + row*64 + col]
  u32* Vtd = (u32*)(smem + 16384);             // [buf*2048 + row*32 + col]
  u32* PTd = (u32*)(smem + 32768) + w * 512;   // per-wave [16*32]

  // V staging: thread handles key-pair column kkp, d-rows dc*8 .. dc*8+7
  const int kkp = lane & 31;
  const int dc  = 2 * w + (lane >> 5);

  // K staging (R6 swizzle)
  const int ksr = w * 16 + (lane >> 3);
  const int ksc = (((lane & 7) ^ ((lane >> 3) & 7)) * 8);
  const int kco0 = ((fg) ^ (fr & 7)) * 8;
  const int kco1 = ((4 + fg) ^ (fr & 7)) * 8;

  // swizzled chunk offsets for PTd/Vtd reads (dwords)
  const int cro0 = 4 * ((fg) ^ (fr & 7));
  const int cro1 = 4 * ((4 + fg) ^ (fr & 7));
  const int pwo  = 4 * (fr & 7);

  const f32x4 zero = {0.f, 0.f, 0.f, 0.f};

  const int q0 = qt * 64;
  const int qw = q0 + w * 16;                  // wave's first q row; lane's q = qw+fr
  const int n  = qt + 1;                       // k-tiles for this q-tile

  // Q fragments (B-operand of S^T); W_q pre-scaled by 0.125
  const bf16x8 qf0 = *(const bf16x8*)(qkv + (rb + qw + fr) * 3072 + hh * 64 + fg * 8);
  const bf16x8 qf1 = *(const bf16x8*)(qkv + (rb + qw + fr) * 3072 + hh * 64 + 32 + fg * 8);

  f32x4 oacc[4];
  #pragma unroll
  for (int mt = 0; mt < 4; ++mt) oacc[mt] = zero;
  float lsum = 0.f;

  // ---- prologue: stage tile 0 into buffer 0 ----
  {
    #pragma unroll
    for (int inst = 0; inst < 2; ++inst)
      gload_lds16(qkv + (rb + ksr + inst * 8) * 3072 + 1024 + hh * 64 + ksc,
                  &Kt[(w * 16 + inst * 8) * 64]);
    const u16* vp = qkv + (rb + 2 * kkp) * 3072 + 2048 + hh * 64 + dc * 8;
    uint4 va = *(const uint4*)vp;
    uint4 vb = *(const uint4*)(vp + 3072);
    u16 a16[8], b16[8];
    *(uint4*)a16 = va; *(uint4*)b16 = vb;
    #pragma unroll
    for (int i = 0; i < 8; ++i)
      Vtd[(dc * 8 + i) * 32 + 4 * ((kkp >> 2) ^ i) + (kkp & 3)] =
          (u32)a16[i] | ((u32)b16[i] << 16);
  }

  int cur = 0;
  for (int it = 0; it < n; ++it) {
    __syncthreads();   // publishes K/V[cur]

    const int  kt       = it * 64;
    const bool havenext = (it + 1) < n;
    uint4 va, vb;
    if (havenext) {
      #pragma unroll
      for (int inst = 0; inst < 2; ++inst)
        gload_lds16(qkv + (rb + kt + 64 + ksr + inst * 8) * 3072 + 1024 + hh * 64 + ksc,
                    &Kt[(cur ^ 1) * 4096 + (w * 16 + inst * 8) * 64]);
      const u16* vp = qkv + (rb + kt + 64 + 2 * kkp) * 3072 + 2048 + hh * 64 + dc * 8;
      va = *(const uint4*)vp;
      vb = *(const uint4*)(vp + 3072);
    }

    // S^T = K Q^T : sacc[nt][r] = S[q=qw+fr][kk = kt + nt*16 + 4*fg + r] (pre-scaled)
    f32x4 sacc[4];
    #pragma unroll
    for (int nt = 0; nt < 4; ++nt) sacc[nt] = zero;
    __builtin_amdgcn_s_setprio(1);
    #pragma unroll
    for (int nt = 0; nt < 4; ++nt) {
      bf16x8 kf0 = *(const bf16x8*)&Kt[cur * 4096 + (nt * 16 + fr) * 64 + kco0];
      sacc[nt] = __builtin_amdgcn_mfma_f32_16x16x32_bf16(kf0, qf0, sacc[nt], 0, 0, 0);
      bf16x8 kf1 = *(const bf16x8*)&Kt[cur * 4096 + (nt * 16 + fr) * 64 + kco1];
      sacc[nt] = __builtin_amdgcn_mfma_f32_16x16x32_bf16(kf1, qf1, sacc[nt], 0, 0, 0);
    }
    __builtin_amdgcn_s_setprio(0);

    // p = exp(s); mask on diagonal tile; spill P^T (v_perm trunc packs)
    if (kt == q0) {
      #pragma unroll
      for (int nt = 0; nt < 4; ++nt) {
        float p[4];
        #pragma unroll
        for (int r = 0; r < 4; ++r) {
          p[r] = (nt * 16 + 4 * fg + r > w * 16 + fr) ? 0.f : __expf(sacc[nt][r]);
          lsum += p[r];
        }
        *(uint2*)&PTd[fr * 32 + ((8 * nt + 2 * fg) ^ pwo)] =
            make_uint2(pack2t(p[0], p[1]), pack2t(p[2], p[3]));
      }
    } else {
      #pragma unroll
      for (int nt = 0; nt < 4; ++nt) {
        float p[4];
        #pragma unroll
        for (int r = 0; r < 4; ++r) {
          p[r] = __expf(sacc[nt][r]);
          lsum += p[r];
        }
        *(uint2*)&PTd[fr * 32 + ((8 * nt + 2 * fg) ^ pwo)] =
            make_uint2(pack2t(p[0], p[1]), pack2t(p[2], p[3]));
      }
    }

    // O^T += V^T P^T
    __builtin_amdgcn_s_setprio(1);
    #pragma unroll
    for (int ks = 0; ks < 2; ++ks) {
      bf16x8 pf = *(const bf16x8*)&PTd[fr * 32 + (ks ? cro1 : cro0)];
      #pragma unroll
      for (int mt = 0; mt < 4; ++mt) {
        bf16x8 vf = *(const bf16x8*)&Vtd[cur * 2048 + (mt * 16 + fr) * 32 + (ks ? cro1 : cro0)];
        oacc[mt] = __builtin_amdgcn_mfma_f32_16x16x32_bf16(vf, pf, oacc[mt], 0, 0, 0);
      }
    }
    __builtin_amdgcn_s_setprio(0);

    if (havenext) {
      u16 a16[8], b16[8];
      *(uint4*)a16 = va; *(uint4*)b16 = vb;
      #pragma unroll
      for (int i = 0; i < 8; ++i)
        Vtd[(cur ^ 1) * 2048 + (dc * 8 + i) * 32 + 4 * ((kkp >> 2) ^ i) + (kkp & 3)] =
            (u32)a16[i] | ((u32)b16[i] << 16);
    }
    cur ^= 1;
  }

  // reduce l over the 4 fg lanes sharing q=fr
  lsum += __shfl_xor(lsum, 16);
  lsum += __shfl_xor(lsum, 32);
  const float inv = 1.f / lsum;

  u16* yp = y + (rb + qw + fr) * 1024 + hh * 64 + 4 * fg;
  #pragma unroll
  for (int mt = 0; mt < 4; ++mt) {
    f32x4 o = oacc[mt];
    *(uint2*)(yp + mt * 16) = make_uint2(pack2(o[0] * inv, o[1] * inv),
                                         pack2(o[2] * inv, o[3] * inv));
  }
}

// ---------------------------------------------------------------------------
extern "C" void kernel_launch(void* const* d_in, const int* in_sizes, int n_in,
                              void* d_out, int out_size, void* d_ws, size_t ws_size,
                              hipStream_t stream)
{
  const float* x    = (const float*)d_in[0];   // [B*L, 1024] fp32
  const float* Wqkv = (const float*)d_in[1];   // [3072, 1024] fp32
  const float* Wo   = (const float*)d_in[2];   // [1024, 1024] fp32
  float* out = (float*)d_out;                  // [B*L, 1024] fp32

  u16* xb    = (u16*)d_ws;                      // [4096,1024]  8 MiB
  u16* Wqkvb = xb    + (size_t)4096 * 1024;     // [3072,1024]  6 MiB
  u16* Wob   = Wqkvb + (size_t)3072 * 1024;     // [1024,1024]  2 MiB
  u16* qkv   = Wob   + (size_t)1024 * 1024;     // [4096,3072] 24 MiB
  u16* y     = qkv   + (size_t)4096 * 3072;     // [4096,1024]  8 MiB

  cvt3_kernel<<<dim3(2048), dim3(256), 0, stream>>>(
      (const float4*)x,    (uint2*)xb,    4096 * 1024 / 4,
      (const float4*)Wqkv, (uint2*)Wqkvb, 3072 * 1024 / 4,
      (const float4*)Wo,   (uint2*)Wob,   1024 * 1024 / 4);

  // qkv = x @ Wqkv^T   (M=4096, N=3072, K=1024)  [R6 config, unchanged]
  gemm_bt_kernel<false, 128, false><<<dim3(3072 / 128, 4096 / 128), dim3(256), 0, stream>>>(
      xb, Wqkvb, qkv, 1024, 3072);
  // causal MHA -> y [4096, 1024] bf16  (R10: 256-thr blocks, 4 blocks/CU)
  attn_mfma_kernel<<<dim3(B_ * H_, 32), dim3(256), 0, stream>>>(qkv, y);
  // out = y @ Wo^T     (M=4096, N=1024, K=1024), fp32 out
  gemm_bt_kernel<true, 64, true><<<dim3(1024 / 64, 4096 / 128), dim3(256), 0, stream>>>(
      y, Wob, out, 1024, 1024);
}